// Round 7
// baseline (2839.936 us; speedup 1.0000x reference)
//
#include <hip/hip_runtime.h>
#include <cstdint>
#include <cstddef>

typedef _Float16 f16;
typedef _Float16 f16x8 __attribute__((ext_vector_type(8)));
typedef _Float16 f16x2 __attribute__((ext_vector_type(2)));
typedef float f32x4 __attribute__((ext_vector_type(4)));

#define B_ 64
#define I_ 128
#define H_ 256
#define T_ 1024
#define BT_ (B_*T_)

// ---------- helpers ----------
__device__ __forceinline__ uint32_t pack2_f16(float a, float b) {
  union { f16 h; uint16_t u; } ua, ub;
  ua.h = (f16)a; ub.h = (f16)b;
  return ((uint32_t)ub.u << 16) | (uint32_t)ua.u;
}

__device__ __forceinline__ float fdot2_u(uint32_t w, uint32_t x, float acc) {
  union { uint32_t u; f16x2 h; } uw, ux;
  uw.u = w; ux.u = x;
  return __builtin_amdgcn_fdot2(uw.h, ux.h, acc, false);
}

// stable tanh
__device__ __forceinline__ float tanh_stable(float s) {
  float a = fabsf(s);
  float e = __expf(-2.f * a);
  float t = (1.f - e) * __fdividef(1.f, 1.f + e);
  return s < 0.f ? -t : t;
}

// MFMA fragment load: row-major LDS row pointer, k-offsets {k0+g4..+3, k0+16+g4..+3}.
// Same map used for A and B fragments -> correct for any bijective per-lane
// k-permutation (verified R3==R4: MFMA GEMM output matched fdot2 GEMM output).
__device__ __forceinline__ f16x8 load_frag(const f16* row, int k0, int g4) {
  union { uint32_t u[4]; f16x8 h; } r;
  const uint32_t* p0 = (const uint32_t*)(row + k0 + g4);
  const uint32_t* p1 = (const uint32_t*)(row + k0 + 16 + g4);
  r.u[0] = p0[0]; r.u[1] = p0[1];
  r.u[2] = p1[0]; r.u[3] = p1[1];
  return r.h;
}

// ---------- K0: transpose Delta [B,I,T] -> Dt f16 [B,T,I] ----------
__global__ void k_transpose_d(const float* __restrict__ D, f16* __restrict__ Dt) {
  __shared__ float tile[64][65];
  int t0 = blockIdx.x * 64, i0 = blockIdx.y * 64, b = blockIdx.z;
  int tx = threadIdx.x, ty = threadIdx.y;  // 64 x 4
  #pragma unroll
  for (int r = 0; r < 16; ++r) {
    int il = ty + r * 4;
    tile[il][tx] = D[((size_t)(b * I_ + i0 + il)) * T_ + t0 + tx];
  }
  __syncthreads();
  #pragma unroll
  for (int r = 0; r < 16; ++r) {
    int tl = ty + r * 4;
    Dt[((size_t)(b * T_ + t0 + tl)) * I_ + i0 + tx] = (f16)tile[tx][tl];
  }
}

// ---------- K_w: weight prep (simple blob layouts, verified R5/R6) ----------
// blob1[c*1024+th], c<64: row j1=th>>1 of [Whz|Whr], k-half kh=th&1, k=kh*128+2c.
// blob2[c*1024+th], c<32: row j2=th>>2 of Whh, k-quarter kq=th&3, k=kq*64+2c.
__global__ void k_prep(const float* __restrict__ Wdgx, const float* __restrict__ bdgx,
                       const float* __restrict__ Wdgh, const float* __restrict__ bdgh,
                       const float* __restrict__ Wxz, const float* __restrict__ Whz,
                       const float* __restrict__ Wmz, const float* __restrict__ bmz,
                       const float* __restrict__ Wxr, const float* __restrict__ Whr,
                       const float* __restrict__ Wmr,
                       const float* __restrict__ Wxh, const float* __restrict__ Whh,
                       const float* __restrict__ Wmh, const float* __restrict__ bmh,
                       f16* __restrict__ Wg, float* __restrict__ bg,
                       f16* __restrict__ W3, float* __restrict__ b3,
                       uint32_t* __restrict__ blob1, uint32_t* __restrict__ blob2) {
  int tid = blockIdx.x * blockDim.x + threadIdx.x;
  int nth = gridDim.x * blockDim.x;
  // Wg [384][128]: rows 0-127 Wdgx, 128-383 Wdgh
  for (int idx = tid; idx < 384 * 128; idx += nth) {
    int j = idx >> 7, k = idx & 127;
    float v = (j < 128) ? Wdgx[j * 128 + k] : Wdgh[(j - 128) * 128 + k];
    Wg[idx] = (f16)v;
  }
  for (int j = tid; j < 384; j += nth) bg[j] = (j < 128) ? bdgx[j] : bdgh[j - 128];
  // W3 [768][256]: row j: [Wx*(128) | Wm*(128)], j blocks: z,r,h
  for (int idx = tid; idx < 768 * 256; idx += nth) {
    int j = idx >> 8, c = idx & 255;
    const float* Wx = (j < 256) ? Wxz : ((j < 512) ? Wxr : Wxh);
    const float* Wm = (j < 256) ? Wmz : ((j < 512) ? Wmr : Wmh);
    int jj = j & 255;
    float v = (c < 128) ? Wx[jj * 128 + c] : Wm[jj * 128 + (c - 128)];
    W3[idx] = (f16)v;
  }
  for (int j = tid; j < 768; j += nth)
    b3[j] = (j < 256) ? bmz[j] : ((j < 512) ? 0.0f : bmh[j - 512]);
  // blob1 (simple layout)
  for (int idx = tid; idx < 64 * 1024; idx += nth) {
    int c = idx >> 10, th = idx & 1023;
    int j1 = th >> 1, kh = th & 1;
    int k = kh * 128 + c * 2;
    const float* src = (j1 < 256) ? Whz : Whr;
    int jr = j1 & 255;
    blob1[idx] = pack2_f16(src[jr * 256 + k], src[jr * 256 + k + 1]);
  }
  // blob2 (simple layout)
  for (int idx = tid; idx < 32 * 1024; idx += nth) {
    int c = idx >> 10, th = idx & 1023;
    int j2 = th >> 2, kq = th & 3;
    int k = kq * 64 + c * 2;
    blob2[idx] = pack2_f16(Whh[j2 * 256 + k], Whh[j2 * 256 + k + 1]);
  }
}

// ---------- K1 (MFMA): Gx/Gh = exp(-relu(Dt @ Wg^T + bg)) ----------
__global__ __launch_bounds__(256) void k_gemm1(const f16* __restrict__ A,
                                               const f16* __restrict__ W,
                                               const float* __restrict__ bias,
                                               float* __restrict__ Gx,
                                               f16* __restrict__ Gh) {
  __shared__ __align__(16) f16 As[64][136];
  __shared__ __align__(16) f16 Ws[128][136];
  int m0 = blockIdx.x * 64, n0 = blockIdx.y * 128;
  int tid = threadIdx.x;
  { // A: 64 rows x 128 f16
    int r = tid >> 2, sgm = tid & 3;
    const uint4* src = (const uint4*)(A + (size_t)(m0 + r) * 128 + sgm * 32);
    uint4* dst = (uint4*)(&As[r][sgm * 32]);
    #pragma unroll
    for (int q = 0; q < 4; ++q) dst[q] = src[q];
  }
  { // W: 128 rows x 128 f16
    int r = tid >> 1, hf = tid & 1;
    const uint4* src = (const uint4*)(W + (size_t)(n0 + r) * 128 + hf * 64);
    uint4* dst = (uint4*)(&Ws[r][hf * 64]);
    #pragma unroll
    for (int q = 0; q < 8; ++q) dst[q] = src[q];
  }
  __syncthreads();
  int w = tid >> 6, l = tid & 63;
  int lr = l & 15, g4 = (l >> 4) * 4;
  f32x4 acc[8] = {};
  #pragma unroll
  for (int kk = 0; kk < 4; ++kk) {
    int k0 = kk * 32;
    f16x8 a = load_frag(&As[w * 16 + lr][0], k0, g4);
    #pragma unroll
    for (int nt = 0; nt < 8; ++nt) {
      f16x8 bf = load_frag(&Ws[nt * 16 + lr][0], k0, g4);
      acc[nt] = __builtin_amdgcn_mfma_f32_16x16x32_f16(a, bf, acc[nt], 0, 0, 0);
    }
  }
  int row4 = (l >> 4) * 4;
  #pragma unroll
  for (int nt = 0; nt < 8; ++nt) {
    int n = n0 + nt * 16 + lr;
    float bv = bias[n];
    #pragma unroll
    for (int reg = 0; reg < 4; ++reg) {
      int m = m0 + w * 16 + row4 + reg;
      float s = acc[nt][reg] + bv;
      float g = __expf(-fmaxf(s, 0.0f));
      if (n < 128) Gx[(size_t)m * 128 + n] = g;
      else         Gh[(size_t)m * 256 + (n - 128)] = (f16)g;
    }
  }
}

// ---------- K3 (MFMA): P = AC @ W3^T + b3 (f16 out) ----------
__global__ __launch_bounds__(256) void k_gemm3(const f16* __restrict__ A,
                                               const f16* __restrict__ W,
                                               const float* __restrict__ bias,
                                               f16* __restrict__ P) {
  __shared__ __align__(16) f16 As[64][136];
  __shared__ __align__(16) f16 Ws[128][136];
  int m0 = blockIdx.x * 64, n0 = blockIdx.y * 128;
  int tid = threadIdx.x;
  int w = tid >> 6, l = tid & 63, lr = l & 15, g4 = (l >> 4) * 4;
  f32x4 acc[8] = {};
  for (int kh = 0; kh < 2; ++kh) {
    {
      int r = tid >> 2, sgm = tid & 3;
      const uint4* src = (const uint4*)(A + (size_t)(m0 + r) * 256 + kh * 128 + sgm * 32);
      uint4* dst = (uint4*)(&As[r][sgm * 32]);
      #pragma unroll
      for (int q = 0; q < 4; ++q) dst[q] = src[q];
    }
    {
      int r = tid >> 1, hf = tid & 1;
      const uint4* src = (const uint4*)(W + (size_t)(n0 + r) * 256 + kh * 128 + hf * 64);
      uint4* dst = (uint4*)(&Ws[r][hf * 64]);
      #pragma unroll
      for (int q = 0; q < 8; ++q) dst[q] = src[q];
    }
    __syncthreads();
    #pragma unroll
    for (int kk = 0; kk < 4; ++kk) {
      int k0 = kk * 32;
      f16x8 a = load_frag(&As[w * 16 + lr][0], k0, g4);
      #pragma unroll
      for (int nt = 0; nt < 8; ++nt) {
        f16x8 bf = load_frag(&Ws[nt * 16 + lr][0], k0, g4);
        acc[nt] = __builtin_amdgcn_mfma_f32_16x16x32_f16(a, bf, acc[nt], 0, 0, 0);
      }
    }
    __syncthreads();
  }
  int row4 = (l >> 4) * 4;
  #pragma unroll
  for (int nt = 0; nt < 8; ++nt) {
    int n = n0 + nt * 16 + lr;
    float bv = bias[n];
    #pragma unroll
    for (int reg = 0; reg < 4; ++reg) {
      int m = m0 + w * 16 + row4 + reg;
      P[(size_t)m * 768 + n] = (f16)(acc[nt][reg] + bv);
    }
  }
}

// ---------- K2a: per-segment last-observation summaries ----------
__global__ void k_seg(const float* __restrict__ X, const float* __restrict__ M,
                      float* __restrict__ segX, float* __restrict__ segF) {
  int b = blockIdx.x, s = blockIdx.y, i = threadIdx.x;
  const float* xr = X + ((size_t)(b * I_ + i)) * T_ + s * 128;
  const float* mr = M + ((size_t)(b * I_ + i)) * T_ + s * 128;
  float last = 0.f, seen = 0.f;
  for (int t = 0; t < 128; ++t) {
    float m = mr[t];
    float x = xr[t];
    if (m > 0.f) { last = x; seen = 1.f; }
  }
  segX[((size_t)(b * I_ + i)) * 8 + s] = last;
  segF[((size_t)(b * I_ + i)) * 8 + s] = seen;
}

// ---------- K2b: x_last + double imputation -> AC f16 [BT][256] = [x2 | m] ----------
__global__ void k_x2(const float* __restrict__ X, const float* __restrict__ M,
                     const float* __restrict__ Gx, const float* __restrict__ xmean_p,
                     const float* __restrict__ segX, const float* __restrict__ segF,
                     f16* __restrict__ AC) {
  int b = blockIdx.x, s = blockIdx.y, i = threadIdx.x;
  float xm = xmean_p[0];
  float xl = 0.f;
  const float* sF = segF + ((size_t)(b * I_ + i)) * 8;
  const float* sX = segX + ((size_t)(b * I_ + i)) * 8;
  for (int p = 0; p < s; ++p) { if (sF[p] > 0.f) xl = sX[p]; }
  const float* xr = X + ((size_t)(b * I_ + i)) * T_;
  const float* mr = M + ((size_t)(b * I_ + i)) * T_;
  for (int tl = 0; tl < 128; ++tl) {
    int t = s * 128 + tl;
    float x = xr[t], m = mr[t];
    float gx = Gx[((size_t)(b * T_ + t)) * I_ + i];
    if (m > 0.f) xl = x;  // x_last updated BEFORE imputation (ref order)
    float x1 = m * x + (1.f - m) * (gx * x + (1.f - gx) * xm);
    float x2 = m * x1 + (1.f - m) * (gx * xl + (1.f - gx) * xm);
    size_t o = ((size_t)(b * T_ + t)) * 256;
    AC[o + i] = (f16)x2;
    AC[o + 128 + i] = (f16)m;
  }
}

// ---------- K4: recurrence, simple layout. 1 block (16 waves) per chain. ----------
// stage1: thread tid -> row j1=tid>>1 of [Whz|Whr], k-half kh=tid&1 (128 k = 64 u32).
// stage2: thread tid -> row j2=tid>>2 of Whh, k-quarter kq=tid&3 (64 k = 32 u32).
__global__ __launch_bounds__(1024) void k_recur(
    const f16* __restrict__ Gh, const f16* __restrict__ P,
    const uint32_t* __restrict__ blob1, const uint32_t* __restrict__ blob2,
    float* __restrict__ out) {
  __shared__ __align__(16) f16 hdh[256];
  __shared__ __align__(16) f16 rhdh[256];
  __shared__ __align__(16) float part1s[2][512];
  __shared__ __align__(16) float part2s[4][256];
  int tid = threadIdx.x;
  int b = blockIdx.x;
  int j1 = tid >> 1, kh = tid & 1;
  int j2 = tid >> 2, kq = tid & 3;

  uint32_t w1[64], w2[32];
  #pragma unroll
  for (int c = 0; c < 64; ++c) w1[c] = blob1[c * 1024 + tid];
  #pragma unroll
  for (int c = 0; c < 32; ++c) w2[c] = blob2[c * 1024 + tid];

  const f16* ghp = Gh + (size_t)b * T_ * 256 + tid;          // tid<256
  const f16* pzp = P + (size_t)b * T_ * 768 + tid;           // tid<512
  const f16* php = P + (size_t)b * T_ * 768 + 512 + tid;     // tid<256
  float* outp = out + (size_t)b * T_ * 256 + tid;            // tid<256 (f32 out)

  float h = 0.f, hd = 0.f, z = 0.f;
  float gh_c = 0.f, pzr_c = 0.f, ph_c = 0.f;
  if (tid < 256) gh_c = (float)ghp[0];
  if (tid < 512) pzr_c = (float)pzp[0];
  if (tid < 256) ph_c = (float)php[0];

  for (int t = 0; t < T_; ++t) {
    if (tid < 256) {
      hd = gh_c * h;
      hdh[tid] = (f16)hd;
    }
    __syncthreads();
    // stage1: partial dot for row j1 over k-half kh
    {
      const uint32_t* hdu = (const uint32_t*)hdh;
      float a = 0.f;
      #pragma unroll
      for (int c = 0; c < 64; ++c) a = fdot2_u(w1[c], hdu[kh * 64 + c], a);
      part1s[kh][j1] = a;
    }
    // prefetch next step's rows (hidden under compute)
    float gh_n = 0.f, pzr_n = 0.f, ph_n = 0.f;
    if (t + 1 < T_) {
      if (tid < 256) gh_n = (float)ghp[256];
      if (tid < 512) pzr_n = (float)pzp[768];
      if (tid < 256) ph_n = (float)php[768];
    }
    __syncthreads();
    // finish1: z (tid<256) and r -> r*hd (tid 256..511)
    if (tid < 512) {
      float s = pzr_c + part1s[0][tid] + part1s[1][tid];
      float sig = __fdividef(1.f, 1.f + __expf(-s));
      if (tid < 256) {
        z = sig;
      } else {
        float rr = sig * (float)hdh[tid - 256];
        rhdh[tid - 256] = (f16)rr;
      }
    }
    __syncthreads();
    // stage2: partial dot for row j2 over k-quarter kq
    {
      const uint32_t* rhu = (const uint32_t*)rhdh;
      float a = 0.f;
      #pragma unroll
      for (int c = 0; c < 32; ++c) a = fdot2_u(w2[c], rhu[kq * 32 + c], a);
      part2s[kq][j2] = a;
    }
    __syncthreads();
    // finish2: h_tilde, h_new, store (f32)
    if (tid < 256) {
      float s2 = ph_c + part2s[0][tid] + part2s[1][tid]
                      + part2s[2][tid] + part2s[3][tid];
      float ht = tanh_stable(s2);
      h = (1.f - z) * hd + z * ht;
      outp[0] = h;
    }
    gh_c = gh_n; pzr_c = pzr_n; ph_c = ph_n;
    ghp += 256; pzp += 768; php += 768; outp += 256;
    __syncthreads();  // isolate iterations completely
  }
}

// ---------- workspace layout ----------
static constexpr size_t OFF_P  = 0;                          // f16 [BT][768]  = 100663296 B
static constexpr size_t OFF_DT = 0;                          // f16 [BT][128]  (overlay; dead before K3)
static constexpr size_t OFF_GX = 100663296;                  // f32 [BT][128]  = 33554432
static constexpr size_t OFF_GH = OFF_GX + 33554432;          // f16 [BT][256]  = 33554432
static constexpr size_t OFF_AC = OFF_GH + 33554432;          // f16 [BT][256]  = 33554432
static constexpr size_t OFF_WG = OFF_AC + 33554432;          // f16 [384][128] = 98304
static constexpr size_t OFF_BG = OFF_WG + 98304;             // f32 [384]      = 1536
static constexpr size_t OFF_W3 = OFF_BG + 1536;              // f16 [768][256] = 393216
static constexpr size_t OFF_B3 = OFF_W3 + 393216;            // f32 [768]      = 3072
static constexpr size_t OFF_B1 = OFF_B3 + 3072;              // u32 [64][1024] = 262144
static constexpr size_t OFF_B2 = OFF_B1 + 262144;            // u32 [32][1024] = 131072
static constexpr size_t OFF_SX = OFF_B2 + 131072;            // f32 [B][I][8]  = 262144
static constexpr size_t OFF_SF = OFF_SX + 262144;            // f32 [B][I][8]  = 262144
static constexpr size_t WS_TOTAL = OFF_SF + 262144;          // ~193.4 MiB

extern "C" void kernel_launch(void* const* d_in, const int* in_sizes, int n_in,
                              void* d_out, int out_size, void* d_ws, size_t ws_size,
                              hipStream_t stream) {
  const float* X    = (const float*)d_in[0];
  const float* Mask = (const float*)d_in[1];
  const float* Delta= (const float*)d_in[2];
  const float* xm   = (const float*)d_in[3];
  const float* Wdgx = (const float*)d_in[4];
  const float* bdgx = (const float*)d_in[5];
  const float* Wdgh = (const float*)d_in[6];
  const float* bdgh = (const float*)d_in[7];
  const float* Wxz  = (const float*)d_in[8];
  const float* Whz  = (const float*)d_in[9];
  const float* Wmz  = (const float*)d_in[10];
  const float* bmz  = (const float*)d_in[11];
  const float* Wxr  = (const float*)d_in[12];
  const float* Whr  = (const float*)d_in[13];
  const float* Wmr  = (const float*)d_in[14];
  const float* Wxh  = (const float*)d_in[15];
  const float* Whh  = (const float*)d_in[16];
  const float* Wmh  = (const float*)d_in[17];
  const float* bmh  = (const float*)d_in[18];
  float* out = (float*)d_out;   // f32 output (reference returns float32)
  char* ws = (char*)d_ws;
  if (ws_size < WS_TOTAL) return;  // insufficient scratch: bail cleanly

  f16*      Dt   = (f16*)(ws + OFF_DT);
  f16*      P    = (f16*)(ws + OFF_P);
  float*    Gx   = (float*)(ws + OFF_GX);
  f16*      Gh   = (f16*)(ws + OFF_GH);
  f16*      AC   = (f16*)(ws + OFF_AC);
  f16*      Wg   = (f16*)(ws + OFF_WG);
  float*    bg   = (float*)(ws + OFF_BG);
  f16*      W3   = (f16*)(ws + OFF_W3);
  float*    b3   = (float*)(ws + OFF_B3);
  uint32_t* bl1  = (uint32_t*)(ws + OFF_B1);
  uint32_t* bl2  = (uint32_t*)(ws + OFF_B2);
  float*    segX = (float*)(ws + OFF_SX);
  float*    segF = (float*)(ws + OFF_SF);

  k_prep<<<dim3(64), dim3(256), 0, stream>>>(Wdgx, bdgx, Wdgh, bdgh, Wxz, Whz, Wmz, bmz,
                                             Wxr, Whr, Wmr, Wxh, Whh, Wmh, bmh,
                                             Wg, bg, W3, b3, bl1, bl2);
  k_transpose_d<<<dim3(16, 2, 64), dim3(64, 4), 0, stream>>>(Delta, Dt);
  k_gemm1<<<dim3(1024, 3), dim3(256), 0, stream>>>(Dt, Wg, bg, Gx, Gh);
  k_seg<<<dim3(64, 8), dim3(128), 0, stream>>>(X, Mask, segX, segF);
  k_x2<<<dim3(64, 8), dim3(128), 0, stream>>>(X, Mask, Gx, xm, segX, segF, AC);
  k_gemm3<<<dim3(1024, 6), dim3(256), 0, stream>>>(AC, W3, b3, P);
  k_recur<<<dim3(64), dim3(1024), 0, stream>>>(Gh, P, bl1, bl2, out);
}

// Round 8
// 2271.329 us; speedup vs baseline: 1.2503x; 1.2503x over previous
//
#include <hip/hip_runtime.h>
#include <cstdint>
#include <cstddef>

typedef _Float16 f16;
typedef _Float16 f16x8 __attribute__((ext_vector_type(8)));
typedef _Float16 f16x2 __attribute__((ext_vector_type(2)));
typedef float f32x4 __attribute__((ext_vector_type(4)));

#define B_ 64
#define I_ 128
#define H_ 256
#define T_ 1024
#define BT_ (B_*T_)

// ---------- helpers ----------
__device__ __forceinline__ uint32_t pack2_f16(float a, float b) {
  union { f16 h; uint16_t u; } ua, ub;
  ua.h = (f16)a; ub.h = (f16)b;
  return ((uint32_t)ub.u << 16) | (uint32_t)ua.u;
}

__device__ __forceinline__ float fdot2_u(uint32_t w, uint32_t x, float acc) {
  union { uint32_t u; f16x2 h; } uw, ux;
  uw.u = w; ux.u = x;
  return __builtin_amdgcn_fdot2(uw.h, ux.h, acc, false);
}

// stable tanh
__device__ __forceinline__ float tanh_stable(float s) {
  float a = fabsf(s);
  float e = __expf(-2.f * a);
  float t = (1.f - e) * __fdividef(1.f, 1.f + e);
  return s < 0.f ? -t : t;
}

__device__ __forceinline__ float sigmoidf(float s) {
  return __fdividef(1.f, 1.f + __expf(-s));
}

// MFMA fragment load: row-major LDS row pointer, k-offsets {k0+g4..+3, k0+16+g4..+3}.
// Same map used for A and B fragments -> correct for any bijective per-lane
// k-permutation (verified R3==R4: MFMA GEMM output matched fdot2 GEMM output).
__device__ __forceinline__ f16x8 load_frag(const f16* row, int k0, int g4) {
  union { uint32_t u[4]; f16x8 h; } r;
  const uint32_t* p0 = (const uint32_t*)(row + k0 + g4);
  const uint32_t* p1 = (const uint32_t*)(row + k0 + 16 + g4);
  r.u[0] = p0[0]; r.u[1] = p0[1];
  r.u[2] = p1[0]; r.u[3] = p1[1];
  return r.h;
}

// ---------- K0: transpose Delta [B,I,T] -> Dt f16 [B,T,I] ----------
__global__ void k_transpose_d(const float* __restrict__ D, f16* __restrict__ Dt) {
  __shared__ float tile[64][65];
  int t0 = blockIdx.x * 64, i0 = blockIdx.y * 64, b = blockIdx.z;
  int tx = threadIdx.x, ty = threadIdx.y;  // 64 x 4
  #pragma unroll
  for (int r = 0; r < 16; ++r) {
    int il = ty + r * 4;
    tile[il][tx] = D[((size_t)(b * I_ + i0 + il)) * T_ + t0 + tx];
  }
  __syncthreads();
  #pragma unroll
  for (int r = 0; r < 16; ++r) {
    int tl = ty + r * 4;
    Dt[((size_t)(b * T_ + t0 + tl)) * I_ + i0 + tx] = (f16)tile[tx][tl];
  }
}

// ---------- K_w: weight prep ----------
// blobR/Z/H[c*512+th], c<64: c = rr*32+cc; th: ks=th>>7, rg=th&127.
// row = rg*2+rr of W (256x256), k = ks*64 + cc*2 + {0,1}.
__global__ void k_prep(const float* __restrict__ Wdgx, const float* __restrict__ bdgx,
                       const float* __restrict__ Wdgh, const float* __restrict__ bdgh,
                       const float* __restrict__ Wxz, const float* __restrict__ Whz,
                       const float* __restrict__ Wmz, const float* __restrict__ bmz,
                       const float* __restrict__ Wxr, const float* __restrict__ Whr,
                       const float* __restrict__ Wmr,
                       const float* __restrict__ Wxh, const float* __restrict__ Whh,
                       const float* __restrict__ Wmh, const float* __restrict__ bmh,
                       f16* __restrict__ Wg, float* __restrict__ bg,
                       f16* __restrict__ W3, float* __restrict__ b3,
                       uint32_t* __restrict__ blobR, uint32_t* __restrict__ blobZ,
                       uint32_t* __restrict__ blobH) {
  int tid = blockIdx.x * blockDim.x + threadIdx.x;
  int nth = gridDim.x * blockDim.x;
  // Wg [384][128]: rows 0-127 Wdgx, 128-383 Wdgh
  for (int idx = tid; idx < 384 * 128; idx += nth) {
    int j = idx >> 7, k = idx & 127;
    float v = (j < 128) ? Wdgx[j * 128 + k] : Wdgh[(j - 128) * 128 + k];
    Wg[idx] = (f16)v;
  }
  for (int j = tid; j < 384; j += nth) bg[j] = (j < 128) ? bdgx[j] : bdgh[j - 128];
  // W3 [768][256]: row j: [Wx*(128) | Wm*(128)], j blocks: z,r,h
  for (int idx = tid; idx < 768 * 256; idx += nth) {
    int j = idx >> 8, c = idx & 255;
    const float* Wx = (j < 256) ? Wxz : ((j < 512) ? Wxr : Wxh);
    const float* Wm = (j < 256) ? Wmz : ((j < 512) ? Wmr : Wmh);
    int jj = j & 255;
    float v = (c < 128) ? Wx[jj * 128 + c] : Wm[jj * 128 + (c - 128)];
    W3[idx] = (f16)v;
  }
  for (int j = tid; j < 768; j += nth)
    b3[j] = (j < 256) ? bmz[j] : ((j < 512) ? 0.0f : bmh[j - 512]);
  // recurrent blobs
  for (int idx = tid; idx < 64 * 512; idx += nth) {
    int c = idx >> 9, th = idx & 511;
    int rr = c >> 5, cc = c & 31;
    int ks = th >> 7, rg = th & 127;
    int row = rg * 2 + rr;
    int k = ks * 64 + cc * 2;
    blobR[idx] = pack2_f16(Whr[row * 256 + k], Whr[row * 256 + k + 1]);
    blobZ[idx] = pack2_f16(Whz[row * 256 + k], Whz[row * 256 + k + 1]);
    blobH[idx] = pack2_f16(Whh[row * 256 + k], Whh[row * 256 + k + 1]);
  }
}

// ---------- K1 (MFMA): Gx/Gh = exp(-relu(Dt @ Wg^T + bg)) ----------
__global__ __launch_bounds__(256) void k_gemm1(const f16* __restrict__ A,
                                               const f16* __restrict__ W,
                                               const float* __restrict__ bias,
                                               float* __restrict__ Gx,
                                               f16* __restrict__ Gh) {
  __shared__ __align__(16) f16 As[64][136];
  __shared__ __align__(16) f16 Ws[128][136];
  int m0 = blockIdx.x * 64, n0 = blockIdx.y * 128;
  int tid = threadIdx.x;
  { // A: 64 rows x 128 f16
    int r = tid >> 2, sgm = tid & 3;
    const uint4* src = (const uint4*)(A + (size_t)(m0 + r) * 128 + sgm * 32);
    uint4* dst = (uint4*)(&As[r][sgm * 32]);
    #pragma unroll
    for (int q = 0; q < 4; ++q) dst[q] = src[q];
  }
  { // W: 128 rows x 128 f16
    int r = tid >> 1, hf = tid & 1;
    const uint4* src = (const uint4*)(W + (size_t)(n0 + r) * 128 + hf * 64);
    uint4* dst = (uint4*)(&Ws[r][hf * 64]);
    #pragma unroll
    for (int q = 0; q < 8; ++q) dst[q] = src[q];
  }
  __syncthreads();
  int w = tid >> 6, l = tid & 63;
  int lr = l & 15, g4 = (l >> 4) * 4;
  f32x4 acc[8] = {};
  #pragma unroll
  for (int kk = 0; kk < 4; ++kk) {
    int k0 = kk * 32;
    f16x8 a = load_frag(&As[w * 16 + lr][0], k0, g4);
    #pragma unroll
    for (int nt = 0; nt < 8; ++nt) {
      f16x8 bf = load_frag(&Ws[nt * 16 + lr][0], k0, g4);
      acc[nt] = __builtin_amdgcn_mfma_f32_16x16x32_f16(a, bf, acc[nt], 0, 0, 0);
    }
  }
  int row4 = (l >> 4) * 4;
  #pragma unroll
  for (int nt = 0; nt < 8; ++nt) {
    int n = n0 + nt * 16 + lr;
    float bv = bias[n];
    #pragma unroll
    for (int reg = 0; reg < 4; ++reg) {
      int m = m0 + w * 16 + row4 + reg;
      float s = acc[nt][reg] + bv;
      float g = __expf(-fmaxf(s, 0.0f));
      if (n < 128) Gx[(size_t)m * 128 + n] = g;
      else         Gh[(size_t)m * 256 + (n - 128)] = (f16)g;
    }
  }
}

// ---------- K3 (MFMA): P = AC @ W3^T + b3 (f16 out) ----------
__global__ __launch_bounds__(256) void k_gemm3(const f16* __restrict__ A,
                                               const f16* __restrict__ W,
                                               const float* __restrict__ bias,
                                               f16* __restrict__ P) {
  __shared__ __align__(16) f16 As[64][136];
  __shared__ __align__(16) f16 Ws[128][136];
  int m0 = blockIdx.x * 64, n0 = blockIdx.y * 128;
  int tid = threadIdx.x;
  int w = tid >> 6, l = tid & 63, lr = l & 15, g4 = (l >> 4) * 4;
  f32x4 acc[8] = {};
  for (int kh = 0; kh < 2; ++kh) {
    {
      int r = tid >> 2, sgm = tid & 3;
      const uint4* src = (const uint4*)(A + (size_t)(m0 + r) * 256 + kh * 128 + sgm * 32);
      uint4* dst = (uint4*)(&As[r][sgm * 32]);
      #pragma unroll
      for (int q = 0; q < 4; ++q) dst[q] = src[q];
    }
    {
      int r = tid >> 1, hf = tid & 1;
      const uint4* src = (const uint4*)(W + (size_t)(n0 + r) * 256 + kh * 128 + hf * 64);
      uint4* dst = (uint4*)(&Ws[r][hf * 64]);
      #pragma unroll
      for (int q = 0; q < 8; ++q) dst[q] = src[q];
    }
    __syncthreads();
    #pragma unroll
    for (int kk = 0; kk < 4; ++kk) {
      int k0 = kk * 32;
      f16x8 a = load_frag(&As[w * 16 + lr][0], k0, g4);
      #pragma unroll
      for (int nt = 0; nt < 8; ++nt) {
        f16x8 bf = load_frag(&Ws[nt * 16 + lr][0], k0, g4);
        acc[nt] = __builtin_amdgcn_mfma_f32_16x16x32_f16(a, bf, acc[nt], 0, 0, 0);
      }
    }
    __syncthreads();
  }
  int row4 = (l >> 4) * 4;
  #pragma unroll
  for (int nt = 0; nt < 8; ++nt) {
    int n = n0 + nt * 16 + lr;
    float bv = bias[n];
    #pragma unroll
    for (int reg = 0; reg < 4; ++reg) {
      int m = m0 + w * 16 + row4 + reg;
      P[(size_t)m * 768 + n] = (f16)(acc[nt][reg] + bv);
    }
  }
}

// ---------- K2a: per-segment last-observation summaries ----------
__global__ void k_seg(const float* __restrict__ X, const float* __restrict__ M,
                      float* __restrict__ segX, float* __restrict__ segF) {
  int b = blockIdx.x, s = blockIdx.y, i = threadIdx.x;
  const float* xr = X + ((size_t)(b * I_ + i)) * T_ + s * 128;
  const float* mr = M + ((size_t)(b * I_ + i)) * T_ + s * 128;
  float last = 0.f, seen = 0.f;
  for (int t = 0; t < 128; ++t) {
    float m = mr[t];
    float x = xr[t];
    if (m > 0.f) { last = x; seen = 1.f; }
  }
  segX[((size_t)(b * I_ + i)) * 8 + s] = last;
  segF[((size_t)(b * I_ + i)) * 8 + s] = seen;
}

// ---------- K2b: x_last + double imputation -> AC f16 [BT][256] = [x2 | m] ----------
__global__ void k_x2(const float* __restrict__ X, const float* __restrict__ M,
                     const float* __restrict__ Gx, const float* __restrict__ xmean_p,
                     const float* __restrict__ segX, const float* __restrict__ segF,
                     f16* __restrict__ AC) {
  int b = blockIdx.x, s = blockIdx.y, i = threadIdx.x;
  float xm = xmean_p[0];
  float xl = 0.f;
  const float* sF = segF + ((size_t)(b * I_ + i)) * 8;
  const float* sX = segX + ((size_t)(b * I_ + i)) * 8;
  for (int p = 0; p < s; ++p) { if (sF[p] > 0.f) xl = sX[p]; }
  const float* xr = X + ((size_t)(b * I_ + i)) * T_;
  const float* mr = M + ((size_t)(b * I_ + i)) * T_;
  for (int tl = 0; tl < 128; ++tl) {
    int t = s * 128 + tl;
    float x = xr[t], m = mr[t];
    float gx = Gx[((size_t)(b * T_ + t)) * I_ + i];
    if (m > 0.f) xl = x;  // x_last updated BEFORE imputation (ref order)
    float x1 = m * x + (1.f - m) * (gx * x + (1.f - gx) * xm);
    float x2 = m * x1 + (1.f - m) * (gx * xl + (1.f - gx) * xm);
    size_t o = ((size_t)(b * T_ + t)) * 256;
    AC[o + i] = (f16)x2;
    AC[o + 128 + i] = (f16)m;
  }
}

// ---------- K4: recurrence. 512 threads/block, 1 block per chain. ----------
// Weights in VGPRs (192 u32/thread), __launch_bounds__(512,2) -> VGPR cap 256,
// no spill. Thread (ks=tid>>7, rg=tid&127) owns rows {rg*2, rg*2+1} x k-slice
// [ks*64, ks*64+64) of each 256x256 matrix. LDS h-vector reads are wave-uniform
// (ks constant per wave) -> broadcast, no bank conflicts.
// Phases: 1) r-dots  2) finish-r -> rhdh  3) z-dots + h~-dots  4) finish+h-update.
__global__ __launch_bounds__(512, 2) void k_recur(
    const f16* __restrict__ Gh, const f16* __restrict__ P,
    const uint32_t* __restrict__ blobR, const uint32_t* __restrict__ blobZ,
    const uint32_t* __restrict__ blobH, float* __restrict__ out) {
  __shared__ __align__(16) f16 hdh[256];
  __shared__ __align__(16) f16 rhdh[256];
  __shared__ __align__(16) float partR[4][256];
  __shared__ __align__(16) float partZ[4][256];
  __shared__ __align__(16) float partH[4][256];
  int tid = threadIdx.x;
  int b = blockIdx.x;
  int ks = tid >> 7, rg = tid & 127;
  bool lo = tid < 256;

  uint32_t wR[64], wZ[64], wH[64];
  #pragma unroll
  for (int c = 0; c < 64; ++c) wR[c] = blobR[c * 512 + tid];
  #pragma unroll
  for (int c = 0; c < 64; ++c) wZ[c] = blobZ[c * 512 + tid];
  #pragma unroll
  for (int c = 0; c < 64; ++c) wH[c] = blobH[c * 512 + tid];

  const f16* gbase = Gh + (size_t)b * T_ * 256;
  const f16* pbase = P + (size_t)b * T_ * 768;
  // rolling prefetch pointers: gh 2 steps ahead, pz/ph 1 step ahead
  const f16* ghp = gbase + 2 * 256 + tid;        // gamma(it+2), lo only
  const f16* pzp = pbase + 768 + tid;            // P[it+1][tid], tid<512
  const f16* php = pbase + 768 + 512 + tid;      // P[it+1][512+tid], lo only
  float* outp = out + (size_t)b * T_ * 256 + tid;

  float h = 0.f, hd = 0.f;
  float pzr_c = (float)pzp[-768];                // P[0][tid]   (tid<512 always)
  float ph_c  = lo ? (float)php[-768] : 0.f;     // P[0][512+tid]
  float gh_u  = lo ? (float)gbase[256 + tid] : 0.f;  // gamma(1), used iter 0 ph4
  if (lo) hdh[tid] = (f16)0.f;                   // hd(0) = gamma(0)*h0 = 0
  __syncthreads();  // A

  for (int it = 0; it < T_; ++it) {
    // prefetch for future iters (consumed: pz/ph next iter, gh next iter ph4)
    float pzr_n = 0.f, ph_n = 0.f, gh_n = 0.f;
    if (it + 1 < T_) {
      pzr_n = (float)pzp[0];
      if (lo) ph_n = (float)php[0];
    }
    if (lo && it + 2 < T_) gh_n = (float)ghp[0];
    pzp += 768; php += 768; ghp += 256;

    const uint32_t* hdu = (const uint32_t*)hdh;
    // phase 1: r-dots (rows 0..255 of Whr), 2 rows x 64k per thread
    {
      float a0 = 0.f, a1 = 0.f;
      #pragma unroll
      for (int cc = 0; cc < 32; ++cc) {
        uint32_t hv = hdu[ks * 32 + cc];
        a0 = fdot2_u(wR[cc], hv, a0);
        a1 = fdot2_u(wR[32 + cc], hv, a1);
      }
      partR[ks][rg * 2 + 0] = a0;
      partR[ks][rg * 2 + 1] = a1;
    }
    __syncthreads();  // B
    // phase 2: finish-r -> rhdh (threads 256..511 hold pr = P[it][256+tr])
    if (!lo) {
      int tr = tid - 256;
      float s = pzr_c + partR[0][tr] + partR[1][tr] + partR[2][tr] + partR[3][tr];
      float r = sigmoidf(s);
      rhdh[tr] = (f16)(r * (float)hdh[tr]);
    }
    __syncthreads();  // C
    // phase 3: z-dots (Whz @ hd) and h~-dots (Whh @ r*hd) concurrently
    {
      const uint32_t* rhu = (const uint32_t*)rhdh;
      float z0 = 0.f, z1 = 0.f, t0 = 0.f, t1 = 0.f;
      #pragma unroll
      for (int cc = 0; cc < 32; ++cc) {
        uint32_t hv = hdu[ks * 32 + cc];
        uint32_t rv = rhu[ks * 32 + cc];
        z0 = fdot2_u(wZ[cc], hv, z0);
        z1 = fdot2_u(wZ[32 + cc], hv, z1);
        t0 = fdot2_u(wH[cc], rv, t0);
        t1 = fdot2_u(wH[32 + cc], rv, t1);
      }
      partZ[ks][rg * 2 + 0] = z0;
      partZ[ks][rg * 2 + 1] = z1;
      partH[ks][rg * 2 + 0] = t0;
      partH[ks][rg * 2 + 1] = t1;
    }
    __syncthreads();  // D
    // phase 4: finish z/h~, update h, store, write hd(it+1)
    if (lo) {
      float sz = pzr_c + partZ[0][tid] + partZ[1][tid] + partZ[2][tid] + partZ[3][tid];
      float z = sigmoidf(sz);
      float s2 = ph_c + partH[0][tid] + partH[1][tid] + partH[2][tid] + partH[3][tid];
      float ht = tanh_stable(s2);
      float hnew = (1.f - z) * hd + z * ht;
      outp[0] = hnew;
      hd = gh_u * hnew;          // hd for step it+1
      hdh[tid] = (f16)hd;
      outp += 256;
    }
    pzr_c = pzr_n; ph_c = ph_n; gh_u = gh_n;
    __syncthreads();  // A (protects hdh write vs phase-1/3 readers)
  }
}

// ---------- workspace layout ----------
static constexpr size_t OFF_P  = 0;                          // f16 [BT][768]  = 100663296 B
static constexpr size_t OFF_DT = 0;                          // f16 [BT][128]  (overlay; dead before K3)
static constexpr size_t OFF_GX = 100663296;                  // f32 [BT][128]  = 33554432
static constexpr size_t OFF_GH = OFF_GX + 33554432;          // f16 [BT][256]  = 33554432
static constexpr size_t OFF_AC = OFF_GH + 33554432;          // f16 [BT][256]  = 33554432
static constexpr size_t OFF_WG = OFF_AC + 33554432;          // f16 [384][128] = 98304
static constexpr size_t OFF_BG = OFF_WG + 98304;             // f32 [384]      = 1536
static constexpr size_t OFF_W3 = OFF_BG + 1536;              // f16 [768][256] = 393216
static constexpr size_t OFF_B3 = OFF_W3 + 393216;            // f32 [768]      = 3072
static constexpr size_t OFF_BR = OFF_B3 + 3072;              // u32 [64][512]  = 131072
static constexpr size_t OFF_BZ = OFF_BR + 131072;            // u32 [64][512]  = 131072
static constexpr size_t OFF_BH = OFF_BZ + 131072;            // u32 [64][512]  = 131072
static constexpr size_t OFF_SX = OFF_BH + 131072;            // f32 [B][I][8]  = 262144
static constexpr size_t OFF_SF = OFF_SX + 262144;            // f32 [B][I][8]  = 262144
static constexpr size_t WS_TOTAL = OFF_SF + 262144;          // ~193.4 MiB

extern "C" void kernel_launch(void* const* d_in, const int* in_sizes, int n_in,
                              void* d_out, int out_size, void* d_ws, size_t ws_size,
                              hipStream_t stream) {
  const float* X    = (const float*)d_in[0];
  const float* Mask = (const float*)d_in[1];
  const float* Delta= (const float*)d_in[2];
  const float* xm   = (const float*)d_in[3];
  const float* Wdgx = (const float*)d_in[4];
  const float* bdgx = (const float*)d_in[5];
  const float* Wdgh = (const float*)d_in[6];
  const float* bdgh = (const float*)d_in[7];
  const float* Wxz  = (const float*)d_in[8];
  const float* Whz  = (const float*)d_in[9];
  const float* Wmz  = (const float*)d_in[10];
  const float* bmz  = (const float*)d_in[11];
  const float* Wxr  = (const float*)d_in[12];
  const float* Whr  = (const float*)d_in[13];
  const float* Wmr  = (const float*)d_in[14];
  const float* Wxh  = (const float*)d_in[15];
  const float* Whh  = (const float*)d_in[16];
  const float* Wmh  = (const float*)d_in[17];
  const float* bmh  = (const float*)d_in[18];
  float* out = (float*)d_out;   // f32 output (reference returns float32)
  char* ws = (char*)d_ws;
  if (ws_size < WS_TOTAL) return;  // insufficient scratch: bail cleanly

  f16*      Dt   = (f16*)(ws + OFF_DT);
  f16*      P    = (f16*)(ws + OFF_P);
  float*    Gx   = (float*)(ws + OFF_GX);
  f16*      Gh   = (f16*)(ws + OFF_GH);
  f16*      AC   = (f16*)(ws + OFF_AC);
  f16*      Wg   = (f16*)(ws + OFF_WG);
  float*    bg   = (float*)(ws + OFF_BG);
  f16*      W3   = (f16*)(ws + OFF_W3);
  float*    b3   = (float*)(ws + OFF_B3);
  uint32_t* blR  = (uint32_t*)(ws + OFF_BR);
  uint32_t* blZ  = (uint32_t*)(ws + OFF_BZ);
  uint32_t* blH  = (uint32_t*)(ws + OFF_BH);
  float*    segX = (float*)(ws + OFF_SX);
  float*    segF = (float*)(ws + OFF_SF);

  k_prep<<<dim3(64), dim3(256), 0, stream>>>(Wdgx, bdgx, Wdgh, bdgh, Wxz, Whz, Wmz, bmz,
                                             Wxr, Whr, Wmr, Wxh, Whh, Wmh, bmh,
                                             Wg, bg, W3, b3, blR, blZ, blH);
  k_transpose_d<<<dim3(16, 2, 64), dim3(64, 4), 0, stream>>>(Delta, Dt);
  k_gemm1<<<dim3(1024, 3), dim3(256), 0, stream>>>(Dt, Wg, bg, Gx, Gh);
  k_seg<<<dim3(64, 8), dim3(128), 0, stream>>>(X, Mask, segX, segF);
  k_x2<<<dim3(64, 8), dim3(128), 0, stream>>>(X, Mask, Gx, xm, segX, segF, AC);
  k_gemm3<<<dim3(1024, 6), dim3(256), 0, stream>>>(AC, W3, b3, P);
  k_recur<<<dim3(64), dim3(512), 0, stream>>>(Gh, P, blR, blZ, blH, out);
}